// Round 11
// baseline (36.987 us; speedup 1.0000x reference)
//
#include <hip/hip_runtime.h>

#define MARGIN 0.1f
#define EPSF   1e-12f
#define BB 32
#define NN 2048
#define DD 128
#define AGENT __HIP_MEMORY_SCOPE_AGENT

// ws layout: dist[BB*NN] f32 | row_loss[BB] f32 | ticket[1] int
// No float atomics anywhere; all float sums fixed-order -> bitwise-deterministic.

// Node 1: dist[b][n]. 32-lane group per row, float4 loads, full-chip grid
// (1024 blocks) to saturate HBM/L3 BW. Resets ticket each launch.
__global__ __launch_bounds__(256) void dist_kernel(const float* __restrict__ anchors,
                                                   const float* __restrict__ feats,
                                                   float* __restrict__ dist,
                                                   int* __restrict__ ticket) {
    const int chunk = blockIdx.x;   // 0..31 (64 rows each)
    const int b     = blockIdx.y;   // 0..31
    const int t     = threadIdx.x;
    const int g     = t >> 5;       // group 0..7
    const int sub   = t & 31;       // lane within group

    if (chunk == 0 && b == 0 && t == 0) *ticket = 0;

    const float4 a4 = ((const float4*)(anchors + b * DD))[sub];
    float a2 = a4.x*a4.x + a4.y*a4.y + a4.z*a4.z + a4.w*a4.w;
    #pragma unroll
    for (int m = 16; m >= 1; m >>= 1) a2 += __shfl_xor(a2, m);
    const float ra    = sqrtf(a2);
    const float inva  = 1.0f / (ra + EPSF);
    const float s_anc = (ra * inva) * (ra * inva);

    const float* fp = feats + ((size_t)b * NN) * DD;
    #pragma unroll
    for (int it = 0; it < 8; ++it) {
        const int n = chunk * 64 + it * 8 + g;
        const float4 f4 = ((const float4*)(fp + (size_t)n * DD))[sub];
        float ss = f4.x*f4.x + f4.y*f4.y + f4.z*f4.z + f4.w*f4.w;
        float dt = a4.x*f4.x + a4.y*f4.y + a4.z*f4.z + a4.w*f4.w;
        #pragma unroll
        for (int m = 16; m >= 1; m >>= 1) {
            ss += __shfl_xor(ss, m);
            dt += __shfl_xor(dt, m);
        }
        const float rf   = sqrtf(ss);
        const float invf = 1.0f / (rf + EPSF);
        const float sq   = s_anc + (rf*invf)*(rf*invf) - 2.0f * dt * inva * invf;
        const float dd   = sqrtf(fmaxf(sq, 1e-12f));
        if (sub == 0) dist[b * NN + n] = dd;
    }
}

// Node 2: one block per batch row. Deterministic ballot compaction (R8-proven
// pattern) + octet brute force over real (pos,neg) pairs + 32-participant
// single-level ticket fan-in (winner sums 32 single-writer row losses).
__global__ __launch_bounds__(1024) void pair_kernel(const float* __restrict__ dist,
                                                    const int* __restrict__ tgt,
                                                    float* __restrict__ row_loss,
                                                    int* __restrict__ ticket,
                                                    float* __restrict__ out) {
    __shared__ float sd[NN + 32];    // compacted negative distances (+sentinel pad)
    __shared__ float pd[NN];         // compacted positive distances
    __shared__ int   cntk[32], posk[32], pref[33], ppref[33];
    __shared__ int   lastflag;
    __shared__ float sacc[16];

    const int b    = blockIdx.x;    // 0..31
    const int t    = threadIdx.x;   // 0..1023
    const int lane = t & 63;
    const int w    = t >> 6;        // wave 0..15

    const float* db = dist + b * NN;
    const int*   tb = tgt  + b * NN;

    // Pass 1: flags + per-(k,wave) counts; slot q = k*16+w follows j-order.
    float dvv[2]; bool ngg[2], pgg[2];
    #pragma unroll
    for (int k = 0; k < 2; ++k) {
        const int j = k * 1024 + t;
        dvv[k] = db[j];
        const int tv = tb[j];
        ngg[k] = (tv == 0);
        pgg[k] = (tv > 0);
        const unsigned long long nm = __ballot(ngg[k]);
        const unsigned long long pm = __ballot(pgg[k]);
        if (lane == 0) { cntk[k*16 + w] = __popcll(nm); posk[k*16 + w] = __popcll(pm); }
    }
    __syncthreads();
    if (t == 0) {   // serial exclusive prefixes in fixed j-order: deterministic
        int rn = 0, rp = 0;
        #pragma unroll
        for (int q = 0; q < 32; ++q) {
            pref[q]  = rn; rn += cntk[q];
            ppref[q] = rp; rp += posk[q];
        }
        pref[32] = rn; ppref[32] = rp;
    }
    __syncthreads();

    // Pass 2: scatter at deterministic offsets (sd, pd both sorted by j).
    #pragma unroll
    for (int k = 0; k < 2; ++k) {
        const unsigned long long nm = __ballot(ngg[k]);
        const unsigned long long pm = __ballot(pgg[k]);
        const unsigned long long lm = (1ull << lane) - 1;
        if (ngg[k]) sd[pref[k*16 + w]  + __popcll(nm & lm)] = dvv[k];
        if (pgg[k]) pd[ppref[k*16 + w] + __popcll(pm & lm)] = dvv[k];
    }
    __syncthreads();

    const int nn     = pref[32];
    const int np     = ppref[32];
    const int nn_pad = (nn + 31) & ~31;     // multiple of 32 floats = 8 float4 strides
    for (int x = t; x < nn_pad - nn; x += 1024) sd[nn + x] = 1e30f;  // relu -> 0
    __syncthreads();

    // Octet brute force: 8 threads per positive, interleaved float4 stripes.
    float acc = 0.0f;
    {
        const int     s   = t & 7;
        const float4* s4  = (const float4*)sd;
        const int     nf4 = nn_pad >> 2;
        for (int p = t >> 3; p < np; p += 128) {
            const float x = pd[p] + MARGIN;
            float a0 = 0.f, a1 = 0.f, a2 = 0.f, a3 = 0.f;
            #pragma unroll 4
            for (int f = s; f < nf4; f += 8) {
                const float4 q = s4[f];     // 8 distinct 16B lines/wave: conflict-free
                a0 += fmaxf(x - q.x, 0.0f);
                a1 += fmaxf(x - q.y, 0.0f);
                a2 += fmaxf(x - q.z, 0.0f);
                a3 += fmaxf(x - q.w, 0.0f);
            }
            acc += (a0 + a1) + (a2 + a3);
        }
    }

    #pragma unroll
    for (int m = 32; m >= 1; m >>= 1) acc += __shfl_xor(acc, m);
    if (lane == 0) sacc[w] = acc;
    __syncthreads();

    // Per-b loss (single writer) + 32-participant ticket; winner sums all.
    if (t == 0) {
        float rs = 0.0f;
        #pragma unroll
        for (int q = 0; q < 16; ++q) rs += sacc[q];   // fixed order
        const float den = fmaxf((float)np * (float)nn, 1.0f);
        const float v   = (np > 0) ? rs / den : MARGIN;
        __hip_atomic_store(&row_loss[b], v, __ATOMIC_RELEASE, AGENT);
        lastflag = (__hip_atomic_fetch_add(ticket, 1, __ATOMIC_ACQ_REL, AGENT) == BB - 1);
    }
    __syncthreads();

    if (lastflag) {
        float v = 0.0f;
        if (t < BB) v = __hip_atomic_load(&row_loss[t], __ATOMIC_ACQUIRE, AGENT);
        if (t < 64) {
            #pragma unroll
            for (int m = 32; m >= 1; m >>= 1) v += __shfl_xor(v, m);  // fixed tree
            if (t == 0) out[0] = v;
        }
    }
}

extern "C" void kernel_launch(void* const* d_in, const int* in_sizes, int n_in,
                              void* d_out, int out_size, void* d_ws, size_t ws_size,
                              hipStream_t stream) {
    const float* anchors = (const float*)d_in[0];
    const float* feats   = (const float*)d_in[1];
    const int*   tgt     = (const int*)d_in[2];
    float*       out     = (float*)d_out;

    float* dist     = (float*)d_ws;             // BB*NN floats
    float* row_loss = dist + BB * NN;           // BB floats
    int*   ticket   = (int*)(row_loss + BB);    // 1 int

    dist_kernel<<<dim3(32, 32), 256, 0, stream>>>(anchors, feats, dist, ticket);
    pair_kernel<<<BB, 1024, 0, stream>>>(dist, tgt, row_loss, ticket, out);
}